// Round 5
// baseline (962.042 us; speedup 1.0000x reference)
//
#include <hip/hip_runtime.h>

#define N_NODES 100000
#define N_EDGES 3200000
#define IN_DIM  512
#define HD_DIM  256
#define OUT_DIM 128

#define NBINS 391          // bins of 256 rows: bin = row >> 8
#define EPT   16           // edges per thread in binning passes
#define EPB   (256 * EPT)  // edges per block = 4096

#define LDSW 36            // LDS row stride in ushorts (72 B): 2-way writes, conflict-free reads

typedef short   short8  __attribute__((ext_vector_type(8)));
typedef unsigned short ushort8 __attribute__((ext_vector_type(8)));
typedef float   floatx4 __attribute__((ext_vector_type(4)));

__device__ __forceinline__ unsigned short f2bf(float f) {
    unsigned int u = __float_as_uint(f);
    u += 0x7fffu + ((u >> 16) & 1u);   // round-to-nearest-even
    return (unsigned short)(u >> 16);
}

// ---------------- streaming fp32 -> bf16 convert ----------------

__global__ __launch_bounds__(256) void cvt_bf16(const float* __restrict__ in,
                                                unsigned int* __restrict__ out, long n4) {
    long i = (long)blockIdx.x * 256 + threadIdx.x;
    long stride = (long)gridDim.x * 256;
    for (; i < n4; i += stride) {
        float4 f = ((const float4*)in)[i];
        uint2 o;
        o.x = (unsigned)f2bf(f.x) | ((unsigned)f2bf(f.y) << 16);
        o.y = (unsigned)f2bf(f.z) | ((unsigned)f2bf(f.w) << 16);
        ((uint2*)out)[i] = o;
    }
}

// ---------------- CSR build: two-level binned counting sort ----------------

__global__ __launch_bounds__(256) void bin_count(const int* __restrict__ erow,
                                                 int* __restrict__ gbin, int E) {
    __shared__ int hist[NBINS];
    for (int i = threadIdx.x; i < NBINS; i += 256) hist[i] = 0;
    __syncthreads();
    long base = (long)blockIdx.x * EPB + threadIdx.x * EPT;
    if (base < E) {
        const int4* p = (const int4*)(erow + base);
#pragma unroll
        for (int v = 0; v < 4; v++) {
            int4 r4 = p[v];
            atomicAdd(&hist[r4.x >> 8], 1);
            atomicAdd(&hist[r4.y >> 8], 1);
            atomicAdd(&hist[r4.z >> 8], 1);
            atomicAdd(&hist[r4.w >> 8], 1);
        }
    }
    __syncthreads();
    for (int i = threadIdx.x; i < NBINS; i += 256)
        if (hist[i]) atomicAdd(&gbin[i], hist[i]);
}

__global__ void bin_scan(const int* __restrict__ gbin, int* __restrict__ bin_base,
                         int* __restrict__ gcursor, int* __restrict__ rowptr) {
    __shared__ int sd[512];
    int v = (threadIdx.x < NBINS) ? gbin[threadIdx.x] : 0;
    sd[threadIdx.x] = v;
    __syncthreads();
    for (int off = 1; off < 512; off <<= 1) {
        int add = (threadIdx.x >= off) ? sd[threadIdx.x - off] : 0;
        __syncthreads();
        sd[threadIdx.x] += add;
        __syncthreads();
    }
    if (threadIdx.x < NBINS) {
        int ex = sd[threadIdx.x] - v;
        bin_base[threadIdx.x] = ex;
        gcursor[threadIdx.x] = ex;
    }
    if (threadIdx.x == 0) { bin_base[NBINS] = N_EDGES; rowptr[N_NODES] = N_EDGES; }
}

// packed bin entry: x = (row_local << 20) | col, y = bits(val)
__global__ __launch_bounds__(256) void bin_scatter(const int* __restrict__ erow,
                                                   const int* __restrict__ ecol,
                                                   const float* __restrict__ eval,
                                                   int* __restrict__ gcursor,
                                                   uint2* __restrict__ binned, int E) {
    __shared__ int hist[NBINS];
    __shared__ int cur[NBINS];
    for (int i = threadIdx.x; i < NBINS; i += 256) hist[i] = 0;
    __syncthreads();
    long base = (long)blockIdx.x * EPB + threadIdx.x * EPT;
    int rows[EPT];
    const bool valid = base < E;   // chunks are all-in or all-out (E % 16 == 0)
    if (valid) {
        const int4* p = (const int4*)(erow + base);
#pragma unroll
        for (int v = 0; v < 4; v++) {
            int4 r = p[v];
            rows[4 * v + 0] = r.x; rows[4 * v + 1] = r.y;
            rows[4 * v + 2] = r.z; rows[4 * v + 3] = r.w;
        }
#pragma unroll
        for (int u = 0; u < EPT; u++) atomicAdd(&hist[rows[u] >> 8], 1);
    }
    __syncthreads();
    for (int i = threadIdx.x; i < NBINS; i += 256) {
        int h = hist[i];
        cur[i] = h ? atomicAdd(&gcursor[i], h) : 0;
    }
    __syncthreads();
    if (valid) {
        const int4*   pc = (const int4*)(ecol + base);
        const float4* pv = (const float4*)(eval + base);
#pragma unroll
        for (int v = 0; v < 4; v++) {
            int4 c4 = pc[v];
            float4 v4 = pv[v];
            int   cs[4] = {c4.x, c4.y, c4.z, c4.w};
            float vs[4] = {v4.x, v4.y, v4.z, v4.w};
#pragma unroll
            for (int u = 0; u < 4; u++) {
                int r = rows[4 * v + u];
                int pos = atomicAdd(&cur[r >> 8], 1);
                binned[pos] = make_uint2(((unsigned)(r & 255) << 20) | (unsigned)cs[u],
                                         __float_as_uint(vs[u]));
            }
        }
    }
}

// one workgroup per bin: local 256-row histogram -> rowptr + row-sorted CSR
__global__ __launch_bounds__(256) void bin_finalize(const int* __restrict__ bin_base,
                                                    const uint2* __restrict__ binned,
                                                    int* __restrict__ rowptr,
                                                    uint2* __restrict__ csr) {
    __shared__ int hist[256];
    __shared__ int cur[256];
    const int b = blockIdx.x;
    const int s = bin_base[b], e = bin_base[b + 1];
    const int t = threadIdx.x;
    hist[t] = 0;
    __syncthreads();
    for (int i = s + t; i < e; i += 256)
        atomicAdd(&hist[binned[i].x >> 20], 1);
    __syncthreads();
    int v = hist[t];
    for (int off = 1; off < 256; off <<= 1) {
        int add = (t >= off) ? hist[t - off] : 0;
        __syncthreads();
        hist[t] += add;
        __syncthreads();
    }
    int excl = hist[t] - v;
    int r = (b << 8) + t;
    if (r < N_NODES) rowptr[r] = s + excl;
    cur[t] = s + excl;
    __syncthreads();
    for (int i = s + t; i < e; i += 256) {
        uint2 ev = binned[i];
        int pos = atomicAdd(&cur[ev.x >> 20], 1);
        csr[pos] = make_uint2(ev.x & 0xFFFFFu, ev.y);
    }
}

// ---------------- transpose + fp32->bf16 for weights: in[K][N] -> out[N][K] ----------------

__global__ void transpose_bf16(const float* __restrict__ in, unsigned short* __restrict__ out,
                               int K, int N) {
    int idx = blockIdx.x * blockDim.x + threadIdx.x;
    if (idx < K * N) {
        int k = idx / N, n = idx - k * N;
        out[n * K + k] = f2bf(in[idx]);
    }
}

// ---------------- MFMA bf16 GEMM: C[M,N] = (relu?)A[M,K] @ BT[N,K]^T + bias ----------------
// A is bf16 [M,K]. 128x128 block tile, 256 threads = 4 waves, each wave 64x64.

template <bool RELU_A, bool OUT_BF16>
__global__ __launch_bounds__(256) void gemm_mfma(const unsigned short* __restrict__ A,
                                                 const unsigned short* __restrict__ BT,
                                                 const float* __restrict__ bias,
                                                 void* __restrict__ Cv,
                                                 int M, int N, int K) {
    __shared__ unsigned short As[128 * LDSW];
    __shared__ unsigned short Bs[128 * LDSW];
    const int tid  = threadIdx.x;
    const int lane = tid & 63;
    const int wv   = tid >> 6;
    const int wm   = (wv >> 1) * 64;
    const int wn   = (wv & 1) * 64;
    const int mrow = lane & 15;
    const int q    = lane >> 4;
    const int bm   = blockIdx.x * 128;
    const int bn   = blockIdx.y * 128;

    floatx4 acc[4][4] = {};

    const int srow = tid >> 1;
    const int skh  = (tid & 1) * 16;

    for (int k0 = 0; k0 < K; k0 += 32) {
        {
            const int grow = bm + srow;
            ushort8 u0, u1;
            if (grow < M) {
                const ushort8* p = (const ushort8*)&A[(long)grow * K + k0 + skh];
                u0 = p[0]; u1 = p[1];
                if (RELU_A) {
#pragma unroll
                    for (int v = 0; v < 8; v++) {
                        if (u0[v] & 0x8000u) u0[v] = 0;
                        if (u1[v] & 0x8000u) u1[v] = 0;
                    }
                }
            } else {
                u0 = (ushort8)0; u1 = (ushort8)0;
            }
            ushort8* dst = (ushort8*)&As[srow * LDSW + skh];
            dst[0] = u0;
            dst[1] = u1;
        }
        {
            const int gn = bn + srow;
            const ushort8* p = (const ushort8*)&BT[(long)gn * K + k0 + skh];
            ushort8* dst = (ushort8*)&Bs[srow * LDSW + skh];
            dst[0] = p[0];
            dst[1] = p[1];
        }
        __syncthreads();

        short8 af[4], bf[4];
#pragma unroll
        for (int i = 0; i < 4; i++)
            af[i] = *(const short8*)&As[(wm + i * 16 + mrow) * LDSW + q * 8];
#pragma unroll
        for (int j = 0; j < 4; j++)
            bf[j] = *(const short8*)&Bs[(wn + j * 16 + mrow) * LDSW + q * 8];
#pragma unroll
        for (int i = 0; i < 4; i++)
#pragma unroll
            for (int j = 0; j < 4; j++)
                acc[i][j] = __builtin_amdgcn_mfma_f32_16x16x32_bf16(af[i], bf[j], acc[i][j], 0, 0, 0);
        __syncthreads();
    }

#pragma unroll
    for (int i = 0; i < 4; i++) {
#pragma unroll
        for (int r = 0; r < 4; r++) {
            const int row = bm + wm + i * 16 + q * 4 + r;
            if (row < M) {
#pragma unroll
                for (int j = 0; j < 4; j++) {
                    const int col = bn + wn + j * 16 + mrow;
                    float v = acc[i][j][r] + bias[col];
                    if (OUT_BF16)
                        ((unsigned short*)Cv)[(long)row * N + col] = f2bf(v);
                    else
                        ((float*)Cv)[(long)row * N + col] = v;
                }
            }
        }
    }
}

// ---------------- CSR SPMM on bf16 H: one wave per row, shfl-broadcast edges ----------------

__global__ __launch_bounds__(256) void spmm_bf16(const int* __restrict__ rowptr,
                                                 const uint2* __restrict__ edges,
                                                 const unsigned short* __restrict__ Hin,
                                                 unsigned short* __restrict__ Hout) {
    const int wave = threadIdx.x >> 6;
    const int lane = threadIdx.x & 63;
    const int r = blockIdx.x * 4 + wave;
    if (r >= N_NODES) return;
    const int s = rowptr[r];
    const int e = rowptr[r + 1];
    const uint2* __restrict__ Hv = (const uint2*)Hin;  // row = 64 uint2
    float a0 = 0.f, a1 = 0.f, a2 = 0.f, a3 = 0.f;

    for (int base = s; base < e; base += 64) {
        int idx = base + lane;
        uint2 ev = (idx < e) ? edges[idx] : make_uint2(0u, 0u);
        int cnt = e - base;
        if (cnt > 64) cnt = 64;
        for (int j0 = 0; j0 < cnt; j0 += 8) {
            uint2 h[8];
            float v[8];
#pragma unroll
            for (int u = 0; u < 8; u++) {
                int   c = __shfl((int)ev.x, j0 + u);
                v[u]    = __uint_as_float((unsigned)__shfl((int)ev.y, j0 + u));
                h[u]    = Hv[((unsigned)c << 6) + lane];
            }
#pragma unroll
            for (int u = 0; u < 8; u++) {
                a0 += v[u] * __uint_as_float(h[u].x << 16);
                a1 += v[u] * __uint_as_float(h[u].x & 0xffff0000u);
                a2 += v[u] * __uint_as_float(h[u].y << 16);
                a3 += v[u] * __uint_as_float(h[u].y & 0xffff0000u);
            }
        }
    }
    uint2 o;
    o.x = (unsigned)f2bf(a0) | ((unsigned)f2bf(a1) << 16);
    o.y = (unsigned)f2bf(a2) | ((unsigned)f2bf(a3) << 16);
    ((uint2*)Hout)[((unsigned)r << 6) + lane] = o;
}

// ---------------- launch ----------------

extern "C" void kernel_launch(void* const* d_in, const int* in_sizes, int n_in,
                              void* d_out, int out_size, void* d_ws, size_t ws_size,
                              hipStream_t stream) {
    const float* x    = (const float*)d_in[0];
    const int*   erow = (const int*)d_in[1];
    const int*   ecol = (const int*)d_in[2];
    const float* eval = (const float*)d_in[3];
    const float* W0   = (const float*)d_in[4];
    const float* b0   = (const float*)d_in[5];
    const float* W1   = (const float*)d_in[6];
    const float* b1   = (const float*)d_in[7];
    float* out = (float*)d_out;

    char* ws = (char*)d_ws;
    size_t off = 0;
    auto alloc = [&](size_t bytes) {
        void* p = ws + off;
        off += (bytes + 255) & ~(size_t)255;
        return p;
    };
    int*            rowptr   = (int*)alloc((N_NODES + 1) * sizeof(int));
    int*            gbin     = (int*)alloc(NBINS * sizeof(int));
    int*            gcursor  = (int*)alloc(NBINS * sizeof(int));
    int*            bin_base = (int*)alloc((NBINS + 1) * sizeof(int));
    uint2*          binned   = (uint2*)alloc((size_t)N_EDGES * sizeof(uint2));
    uint2*          csr      = (uint2*)alloc((size_t)N_EDGES * sizeof(uint2));
    unsigned short* xb       = (unsigned short*)alloc((size_t)N_NODES * IN_DIM * sizeof(unsigned short));
    unsigned short* W0T      = (unsigned short*)alloc((size_t)IN_DIM * HD_DIM * sizeof(unsigned short));
    unsigned short* W1T      = (unsigned short*)alloc((size_t)HD_DIM * OUT_DIM * sizeof(unsigned short));
    unsigned short* Ha       = (unsigned short*)alloc((size_t)N_NODES * HD_DIM * sizeof(unsigned short));
    unsigned short* Hb       = (unsigned short*)alloc((size_t)N_NODES * HD_DIM * sizeof(unsigned short));

    const int nblk = (N_EDGES + EPB - 1) / EPB;  // 782

    // CSR build (ws re-poisoned each launch -> zero the counters)
    hipMemsetAsync(gbin, 0, NBINS * sizeof(int), stream);
    bin_count<<<nblk, 256, 0, stream>>>(erow, gbin, N_EDGES);
    bin_scan<<<1, 512, 0, stream>>>(gbin, bin_base, gcursor, rowptr);
    bin_scatter<<<nblk, 256, 0, stream>>>(erow, ecol, eval, gcursor, binned, N_EDGES);
    bin_finalize<<<NBINS, 256, 0, stream>>>(bin_base, binned, rowptr, csr);

    // x -> bf16 (streaming), weight transpose + convert
    cvt_bf16<<<2048, 256, 0, stream>>>(x, (unsigned int*)xb, (long)N_NODES * IN_DIM / 4);
    transpose_bf16<<<(IN_DIM * HD_DIM + 255) / 256, 256, 0, stream>>>(W0, W0T, IN_DIM, HD_DIM);
    transpose_bf16<<<(HD_DIM * OUT_DIM + 255) / 256, 256, 0, stream>>>(W1, W1T, HD_DIM, OUT_DIM);

    // H0 = bf16(xb @ W0 + b0)
    gemm_mfma<false, true><<<dim3((N_NODES + 127) / 128, HD_DIM / 128), 256, 0, stream>>>(
        xb, W0T, b0, Ha, N_NODES, HD_DIM, IN_DIM);

    // H1 = A @ H0 ; H2 = A @ H1
    spmm_bf16<<<(N_NODES + 3) / 4, 256, 0, stream>>>(rowptr, csr, Ha, Hb);
    spmm_bf16<<<(N_NODES + 3) / 4, 256, 0, stream>>>(rowptr, csr, Hb, Ha);

    // out = relu(H2) @ W1 + b1  (fp32 out)
    gemm_mfma<true, false><<<dim3((N_NODES + 127) / 128, OUT_DIM / 128), 256, 0, stream>>>(
        Ha, W1T, b1, out, N_NODES, OUT_DIM, HD_DIM);
}